// Round 19
// baseline (49.699 us; speedup 1.0000x reference)
//
#include <hip/hip_runtime.h>

#define NPRE 32768
#define NPOST 32768
#define RR 64
#define BATCH 512
#define KSPLIT 128
#define KCHUNK 256  // NPRE / KSPLIT

typedef float f32x4 __attribute__((ext_vector_type(4)));
typedef __bf16 bf16x8 __attribute__((ext_vector_type(8)));
typedef unsigned short u16;
typedef unsigned int u32;

static __device__ __forceinline__ float bf2f(u32 s) {
  return __builtin_bit_cast(float, s << 16);
}
// HW packed f32->bf16 (RNE), low16 = first arg (verified round 12).
static __device__ __forceinline__ u32 cvtpk(float lo, float hi) {
  u32 r;
  asm("v_cvt_pk_bf16_f32 %0, %1, %2" : "=v"(r) : "v"(lo), "v"(hi));
  return r;
}
static __device__ __forceinline__ bf16x8 pack8(f32x4 lo, f32x4 hi) {
  union { u32 w[4]; bf16x8 v; } u;
  u.w[0] = cvtpk(lo.x, lo.y);
  u.w[1] = cvtpk(lo.z, lo.w);
  u.w[2] = cvtpk(hi.x, hi.y);
  u.w[3] = cvtpk(hi.z, hi.w);
  return u.v;
}

// ---- GEMM1 (frozen): zp[kc][b][r] = S[b][kslice] @ V[kslice][r] -----------
__global__ __launch_bounds__(256, 4) void k1(const float* __restrict__ S,
                                             const float* __restrict__ V,
                                             u16* __restrict__ zp) {
  int bid = blockIdx.x;
  int eff = (bid & 7) * 128 + (bid >> 3);  // bijective XCD swizzle (1024 % 8 == 0)
  int grp = eff & 7;
  int kc = eff >> 3;                       // XCD-contiguous kc range
  int lane = threadIdx.x & 63;
  int w = threadIdx.x >> 6;
  int mt = grp * 4 + w;                    // 0..31
  int l15 = lane & 15, g = lane >> 4;
  const float* A = S + (size_t)(mt * 16 + l15) * NPRE + kc * KCHUNK + g * 8;
  const float* Vb = V + (size_t)(kc * KCHUNK + g * 8) * RR + l15;
  f32x4 acc[4] = {};
#pragma unroll 2
  for (int ks = 0; ks < KCHUNK / 32; ++ks) {
    f32x4 a0 = *reinterpret_cast<const f32x4*>(A + ks * 32);
    f32x4 a1 = *reinterpret_cast<const f32x4*>(A + ks * 32 + 4);
    bf16x8 af = pack8(a0, a1);
    const float* Vk = Vb + (size_t)ks * 32 * RR;
    bf16x8 bfr[4];
#pragma unroll
    for (int tt = 0; tt < 4; ++tt) {
      f32x4 lo, hi;
      lo.x = Vk[0 * RR + tt * 16]; lo.y = Vk[1 * RR + tt * 16];
      lo.z = Vk[2 * RR + tt * 16]; lo.w = Vk[3 * RR + tt * 16];
      hi.x = Vk[4 * RR + tt * 16]; hi.y = Vk[5 * RR + tt * 16];
      hi.z = Vk[6 * RR + tt * 16]; hi.w = Vk[7 * RR + tt * 16];
      bfr[tt] = pack8(lo, hi);
    }
    acc[0] = __builtin_amdgcn_mfma_f32_16x16x32_bf16(af, bfr[0], acc[0], 0, 0, 0);
    acc[1] = __builtin_amdgcn_mfma_f32_16x16x32_bf16(af, bfr[1], acc[1], 0, 0, 0);
    acc[2] = __builtin_amdgcn_mfma_f32_16x16x32_bf16(af, bfr[2], acc[2], 0, 0, 0);
    acc[3] = __builtin_amdgcn_mfma_f32_16x16x32_bf16(af, bfr[3], acc[3], 0, 0, 0);
  }
  u16* out = zp + ((size_t)kc * BATCH + mt * 16) * RR;
#pragma unroll
  for (int tt = 0; tt < 4; ++tt)
#pragma unroll
    for (int q = 0; q < 4; ++q)
      out[(g * 4 + q) * RR + tt * 16 + l15] = (u16)cvtpk(acc[tt][q], acc[tt][q]);
}

// ---- reduce (frozen, v2): u32 pair loads, cvt_pk out ----------------------
__global__ __launch_bounds__(1024) void k_red(const u16* __restrict__ zp,
                                              u16* __restrict__ zb) {
  __shared__ float pl[4][256], ph[4][256];
  int il = threadIdx.x & 255;
  int tg = threadIdx.x >> 8;
  int i2 = blockIdx.x * 256 + il;  // pair index, outputs {2*i2, 2*i2+1}
  const u32* p = reinterpret_cast<const u32*>(zp) +
                 (size_t)(tg * 32) * (BATCH * RR / 2) + i2;
  float sl = 0.f, sh = 0.f;
#pragma unroll
  for (int j = 0; j < 32; j += 4) {
    u32 w0 = p[(size_t)(j + 0) * (BATCH * RR / 2)];
    u32 w1 = p[(size_t)(j + 1) * (BATCH * RR / 2)];
    u32 w2 = p[(size_t)(j + 2) * (BATCH * RR / 2)];
    u32 w3 = p[(size_t)(j + 3) * (BATCH * RR / 2)];
    sl += (bf2f(w0 & 0xffffu) + bf2f(w1 & 0xffffu)) +
          (bf2f(w2 & 0xffffu) + bf2f(w3 & 0xffffu));
    sh += (bf2f(w0 >> 16) + bf2f(w1 >> 16)) + (bf2f(w2 >> 16) + bf2f(w3 >> 16));
  }
  pl[tg][il] = sl;
  ph[tg][il] = sh;
  __syncthreads();
  if (tg == 0) {
    float lo = (pl[0][il] + pl[1][il]) + (pl[2][il] + pl[3][il]);
    float hi = (ph[0][il] + ph[1][il]) + (ph[2][il] + ph[3][il]);
    reinterpret_cast<u32*>(zb)[i2] = cvtpk(lo, hi);
  }
}

// ---- GEMM2 v12: v10 + doubled stores, SAFE C form (marginal-cost probe) ---
// Each y-store executed twice: plain C store, empty-asm compiler fence (no
// codegen, blocks DSE), plain C store again. Both are compiler-generated
// global_store_dwordx4 (r18's hand-rolled asm store proved unsafe — lesson:
// never hand-roll vmem asm here). Output idempotent.
// Pre-committed read: total +16-23us => store-path-bound, ceiling confirmed,
// revert to v10 next round. total <= ~50 => stores cheap at margin.
__global__ __launch_bounds__(256) void k2(const u16* __restrict__ zv,
                                          const float* __restrict__ U,
                                          float* __restrict__ y) {
  int bid = blockIdx.x;
  int eff = (bid & 7) * 32 + (bid >> 3);  // bijective (256 % 8 == 0)
  int ntile = eff >> 1;                   // 0..127: n-tile of 256 (XCD-contig)
  int bh = eff & 1;                       // batch half (256 rows)
  int n0 = ntile * 256;
  int bb = bh * 256;
  int t = threadIdx.x;
  int lane = t & 63;
  int w = t >> 6;                         // 0..3
  int l15 = lane & 15, g = lane >> 4;

  // U fragments -> registers, once. Wave w owns taus {w+4j}: rows tau*16+l15.
  bf16x8 uA[4], uB[4];
#pragma unroll
  for (int j = 0; j < 4; ++j) {
    int row = (w + 4 * j) * 16 + l15;  // 0..255 within tile
    const float* Up = U + (size_t)(n0 + row) * RR + g * 8;
    f32x4 a = *reinterpret_cast<const f32x4*>(Up);
    f32x4 b = *reinterpret_cast<const f32x4*>(Up + 4);
    f32x4 c = *reinterpret_cast<const f32x4*>(Up + 32);
    f32x4 d = *reinterpret_cast<const f32x4*>(Up + 36);
    uA[j] = pack8(a, b);   // k 0..31 slice
    uB[j] = pack8(c, d);   // k 32..63 slice
  }

  const u16* Ab = zv + (size_t)(bb + l15) * RR + g * 8;
  bf16x8 za = *reinterpret_cast<const bf16x8*>(Ab);
  bf16x8 zc = *reinterpret_cast<const bf16x8*>(Ab + 32);
#pragma unroll
  for (int it = 0; it < 16; ++it) {
    bf16x8 zan = za, zcn = zc;
    if (it < 15) {  // prefetch next tile's zb BEFORE this tile's stores
      const u16* An = Ab + (size_t)(it + 1) * 16 * RR;
      zan = *reinterpret_cast<const bf16x8*>(An);
      zcn = *reinterpret_cast<const bf16x8*>(An + 32);
    }
    f32x4 acc[4] = {};
#pragma unroll
    for (int j = 0; j < 4; ++j) {
      acc[j] = __builtin_amdgcn_mfma_f32_16x16x32_bf16(uA[j], za, acc[j], 0, 0, 0);
      acc[j] = __builtin_amdgcn_mfma_f32_16x16x32_bf16(uB[j], zc, acc[j], 0, 0, 0);
    }
    float* yb = y + (size_t)(bb + it * 16 + l15) * NPOST + n0;
#pragma unroll
    for (int j = 0; j < 4; ++j) {
      f32x4* dst = reinterpret_cast<f32x4*>(yb + (w + 4 * j) * 16 + g * 4);
      *dst = acc[j];
      asm volatile("" ::: "memory");  // compiler fence only: keeps both stores
      *dst = acc[j];
    }
    za = zan;
    zc = zcn;
  }
}

extern "C" void kernel_launch(void* const* d_in, const int* in_sizes, int n_in,
                              void* d_out, int out_size, void* d_ws, size_t ws_size,
                              hipStream_t stream) {
  const float* spikes = (const float*)d_in[0];
  const float* U = (const float*)d_in[1];
  const float* V = (const float*)d_in[2];
  // d_in[3..5]: CSR mask — dead in the reference, unused.
  float* y = (float*)d_out;
  char* ws = (char*)d_ws;
  u16* zp = (u16*)ws;                    // 8 MiB  [KSPLIT][BATCH][RR] bf16
  u16* zb = (u16*)(ws + (8u << 20));     // 64 KiB [BATCH][RR] bf16

  k1<<<1024, 256, 0, stream>>>(spikes, V, zp);
  k_red<<<64, 1024, 0, stream>>>(zp, zb);
  k2<<<256, 256, 0, stream>>>(zb, U, y);
}

// Round 20
// 42.335 us; speedup vs baseline: 1.1740x; 1.1740x over previous
//
#include <hip/hip_runtime.h>

#define NPRE 32768
#define NPOST 32768
#define RR 64
#define BATCH 512
#define KSPLIT 64
#define KCHUNK 512  // NPRE / KSPLIT

typedef float f32x4 __attribute__((ext_vector_type(4)));
typedef __bf16 bf16x8 __attribute__((ext_vector_type(8)));
typedef unsigned short u16;
typedef unsigned int u32;

static __device__ __forceinline__ float bf2f(u32 s) {
  return __builtin_bit_cast(float, s << 16);
}
// HW packed f32->bf16 (RNE), low16 = first arg (verified round 12).
static __device__ __forceinline__ u32 cvtpk(float lo, float hi) {
  u32 r;
  asm("v_cvt_pk_bf16_f32 %0, %1, %2" : "=v"(r) : "v"(lo), "v"(hi));
  return r;
}
static __device__ __forceinline__ bf16x8 pack8(f32x4 lo, f32x4 hi) {
  union { u32 w[4]; bf16x8 v; } u;
  u.w[0] = cvtpk(lo.x, lo.y);
  u.w[1] = cvtpk(lo.z, lo.w);
  u.w[2] = cvtpk(hi.x, hi.y);
  u.w[3] = cvtpk(hi.z, hi.w);
  return u.v;
}

// ---- GEMM1: zp[kc][b][r] = S[b][kslice] @ V[kslice][r], KSPLIT=64 ---------
// 512 blocks (8 grp x 64 kc), 2 blocks/CU. zp halved to 4 MB (-1.3us write).
__global__ __launch_bounds__(256, 4) void k1(const float* __restrict__ S,
                                             const float* __restrict__ V,
                                             u16* __restrict__ zp) {
  int bid = blockIdx.x;
  int eff = (bid & 7) * 64 + (bid >> 3);  // bijective XCD swizzle (512 % 8 == 0)
  int grp = eff & 7;
  int kc = eff >> 3;                       // 0..63, XCD-contiguous
  int lane = threadIdx.x & 63;
  int w = threadIdx.x >> 6;
  int mt = grp * 4 + w;                    // 0..31
  int l15 = lane & 15, g = lane >> 4;
  const float* A = S + (size_t)(mt * 16 + l15) * NPRE + kc * KCHUNK + g * 8;
  const float* Vb = V + (size_t)(kc * KCHUNK + g * 8) * RR + l15;
  f32x4 acc[4] = {};
#pragma unroll 2
  for (int ks = 0; ks < KCHUNK / 32; ++ks) {
    f32x4 a0 = *reinterpret_cast<const f32x4*>(A + ks * 32);
    f32x4 a1 = *reinterpret_cast<const f32x4*>(A + ks * 32 + 4);
    bf16x8 af = pack8(a0, a1);
    const float* Vk = Vb + (size_t)ks * 32 * RR;
    bf16x8 bfr[4];
#pragma unroll
    for (int tt = 0; tt < 4; ++tt) {
      f32x4 lo, hi;
      lo.x = Vk[0 * RR + tt * 16]; lo.y = Vk[1 * RR + tt * 16];
      lo.z = Vk[2 * RR + tt * 16]; lo.w = Vk[3 * RR + tt * 16];
      hi.x = Vk[4 * RR + tt * 16]; hi.y = Vk[5 * RR + tt * 16];
      hi.z = Vk[6 * RR + tt * 16]; hi.w = Vk[7 * RR + tt * 16];
      bfr[tt] = pack8(lo, hi);
    }
    acc[0] = __builtin_amdgcn_mfma_f32_16x16x32_bf16(af, bfr[0], acc[0], 0, 0, 0);
    acc[1] = __builtin_amdgcn_mfma_f32_16x16x32_bf16(af, bfr[1], acc[1], 0, 0, 0);
    acc[2] = __builtin_amdgcn_mfma_f32_16x16x32_bf16(af, bfr[2], acc[2], 0, 0, 0);
    acc[3] = __builtin_amdgcn_mfma_f32_16x16x32_bf16(af, bfr[3], acc[3], 0, 0, 0);
  }
  u16* out = zp + ((size_t)kc * BATCH + mt * 16) * RR;
#pragma unroll
  for (int tt = 0; tt < 4; ++tt)
#pragma unroll
    for (int q = 0; q < 4; ++q)
      out[(g * 4 + q) * RR + tt * 16 + l15] = (u16)cvtpk(acc[tt][q], acc[tt][q]);
}

// ---- reduce: 64 partials, 4 tg x 16 each ----------------------------------
__global__ __launch_bounds__(1024) void k_red(const u16* __restrict__ zp,
                                              u16* __restrict__ zb) {
  __shared__ float pl[4][256], ph[4][256];
  int il = threadIdx.x & 255;
  int tg = threadIdx.x >> 8;
  int i2 = blockIdx.x * 256 + il;  // pair index, outputs {2*i2, 2*i2+1}
  const u32* p = reinterpret_cast<const u32*>(zp) +
                 (size_t)(tg * 16) * (BATCH * RR / 2) + i2;
  float sl = 0.f, sh = 0.f;
#pragma unroll
  for (int j = 0; j < 16; j += 4) {
    u32 w0 = p[(size_t)(j + 0) * (BATCH * RR / 2)];
    u32 w1 = p[(size_t)(j + 1) * (BATCH * RR / 2)];
    u32 w2 = p[(size_t)(j + 2) * (BATCH * RR / 2)];
    u32 w3 = p[(size_t)(j + 3) * (BATCH * RR / 2)];
    sl += (bf2f(w0 & 0xffffu) + bf2f(w1 & 0xffffu)) +
          (bf2f(w2 & 0xffffu) + bf2f(w3 & 0xffffu));
    sh += (bf2f(w0 >> 16) + bf2f(w1 >> 16)) + (bf2f(w2 >> 16) + bf2f(w3 >> 16));
  }
  pl[tg][il] = sl;
  ph[tg][il] = sh;
  __syncthreads();
  if (tg == 0) {
    float lo = (pl[0][il] + pl[1][il]) + (pl[2][il] + pl[3][il]);
    float hi = (ph[0][il] + ph[1][il]) + (ph[2][il] + ph[3][il]);
    reinterpret_cast<u32*>(zb)[i2] = cvtpk(lo, hi);
  }
}

// ---- GEMM2 v13: full-column blocks + depth-4 zb prefetch ring -------------
// 256 blocks x 256 thr, block = n-tile 128 x ALL 512 b (32 it-tiles).
// U redundancy eliminated (8 MB unique, 32 KB/block, register-resident).
// zb loads run a 4-deep static ring (~160cyc slack vs L2 ~200cyc latency).
// Store stream: 64 stores/wave, continuous (v10's winning property, 2x).
__global__ __launch_bounds__(256) void k2(const u16* __restrict__ zv,
                                          const float* __restrict__ U,
                                          float* __restrict__ y) {
  int bid = blockIdx.x;
  int eff = (bid & 7) * 32 + (bid >> 3);  // bijective (256 % 8 == 0)
  int n0 = eff * 128;                     // XCD-contiguous 4096-wide n ranges
  int t = threadIdx.x;
  int lane = t & 63;
  int w = t >> 6;                         // 0..3
  int l15 = lane & 15, g = lane >> 4;

  // U fragments -> registers, once. Wave w owns taus {w, w+4} (rows 0..127).
  bf16x8 uA[2], uB[2];
#pragma unroll
  for (int j = 0; j < 2; ++j) {
    int row = (w + 4 * j) * 16 + l15;
    const float* Up = U + (size_t)(n0 + row) * RR + g * 8;
    f32x4 a = *reinterpret_cast<const f32x4*>(Up);
    f32x4 b = *reinterpret_cast<const f32x4*>(Up + 4);
    f32x4 c = *reinterpret_cast<const f32x4*>(Up + 32);
    f32x4 d = *reinterpret_cast<const f32x4*>(Up + 36);
    uA[j] = pack8(a, b);   // k 0..31 slice
    uB[j] = pack8(c, d);   // k 32..63 slice
  }

  const u16* Ab = zv + (size_t)l15 * RR + g * 8;  // b-row = it*16 + l15
  bf16x8 za[4], zc[4];
#pragma unroll
  for (int p = 0; p < 4; ++p) {
    za[p] = *reinterpret_cast<const bf16x8*>(Ab + (size_t)p * 16 * RR);
    zc[p] = *reinterpret_cast<const bf16x8*>(Ab + (size_t)p * 16 * RR + 32);
  }
#pragma unroll
  for (int it = 0; it < 32; ++it) {
    int cur = it & 3;  // compile-time within unrolled body (rule #20)
    f32x4 acc0 = {}, acc1 = {};
    acc0 = __builtin_amdgcn_mfma_f32_16x16x32_bf16(uA[0], za[cur], acc0, 0, 0, 0);
    acc0 = __builtin_amdgcn_mfma_f32_16x16x32_bf16(uB[0], zc[cur], acc0, 0, 0, 0);
    acc1 = __builtin_amdgcn_mfma_f32_16x16x32_bf16(uA[1], za[cur], acc1, 0, 0, 0);
    acc1 = __builtin_amdgcn_mfma_f32_16x16x32_bf16(uB[1], zc[cur], acc1, 0, 0, 0);
    if (it < 28) {  // refill ring slot BEFORE stores (loads precede stores)
      const u16* An = Ab + (size_t)(it + 4) * 16 * RR;
      za[cur] = *reinterpret_cast<const bf16x8*>(An);
      zc[cur] = *reinterpret_cast<const bf16x8*>(An + 32);
    }
    // D: col=l15 <-> b, row=g*4+q <-> n; lane stores 4 consecutive n (16B)
    float* yb = y + (size_t)(it * 16 + l15) * NPOST + n0;
    *reinterpret_cast<f32x4*>(yb + w * 16 + g * 4) = acc0;
    *reinterpret_cast<f32x4*>(yb + (w + 4) * 16 + g * 4) = acc1;
  }
}

extern "C" void kernel_launch(void* const* d_in, const int* in_sizes, int n_in,
                              void* d_out, int out_size, void* d_ws, size_t ws_size,
                              hipStream_t stream) {
  const float* spikes = (const float*)d_in[0];
  const float* U = (const float*)d_in[1];
  const float* V = (const float*)d_in[2];
  // d_in[3..5]: CSR mask — dead in the reference, unused.
  float* y = (float*)d_out;
  char* ws = (char*)d_ws;
  u16* zp = (u16*)ws;                    // 4 MiB  [KSPLIT=64][BATCH][RR] bf16
  u16* zb = (u16*)(ws + (4u << 20));     // 64 KiB [BATCH][RR] bf16

  k1<<<512, 256, 0, stream>>>(spikes, V, zp);
  k_red<<<64, 1024, 0, stream>>>(zp, zb);
  k2<<<256, 256, 0, stream>>>(zb, U, y);
}